// Round 1
// baseline (306.629 us; speedup 1.0000x reference)
//
#include <hip/hip_runtime.h>
#include <stdint.h>

#define SEQ 2048
#define NTOK 4096          // B*S
#define DM 1024

typedef __bf16 bf16x8 __attribute__((ext_vector_type(8)));
typedef float f32x4 __attribute__((ext_vector_type(4)));

__device__ __forceinline__ unsigned short f2bf(float f) {
  union { float f; unsigned u; } v; v.f = f;
  return (unsigned short)((v.u + 0x7fffu + ((v.u >> 16) & 1u)) >> 16);
}
__device__ __forceinline__ float bf2f(unsigned short s) {
  union { unsigned u; float f; } v; v.u = ((unsigned)s) << 16; return v.f;
}

// async global->LDS, 16B per lane. LDS dest must be wave-uniform base + lane*16.
__device__ __forceinline__ void async16(const unsigned short* g, unsigned short* l) {
  __builtin_amdgcn_global_load_lds(
      (const __attribute__((address_space(1))) void*)g,
      (__attribute__((address_space(3))) void*)l, 16, 0, 0);
}

__global__ __launch_bounds__(256) void cast_f32_bf16(
    const float* __restrict__ src, unsigned short* __restrict__ dst, int n) {
  int i = (blockIdx.x * 256 + threadIdx.x) * 4;
  if (i + 3 < n) {
    float4 f = *(const float4*)(src + i);
    ushort4 o;
    o.x = f2bf(f.x); o.y = f2bf(f.y); o.z = f2bf(f.z); o.w = f2bf(f.w);
    *(ushort4*)(dst + i) = o;
  }
}

// ---- 128x128 GEMM core (m97 pattern): C[m,n] += sum_k A[m,k]*B[n,k] ----
// A: [*,1024] bf16 row-major; B: [*,1024] bf16 row-major (W[e,d] = B^T form).
__device__ __forceinline__ void gemm128_core(
    const unsigned short* __restrict__ A, const unsigned short* __restrict__ Bw,
    int m0, int n0, f32x4 acc[4][4], unsigned short* As, unsigned short* Bs) {
  const int tid = threadIdx.x;
  const int lane = tid & 63;
  const int w = tid >> 6;
  const int wm = (w >> 1) * 64, wn = (w & 1) * 64;
  const int quad = lane >> 4, l16 = lane & 15;
  const int srow = tid >> 2, scol = (tid & 3) * 8;   // staging: flat = tid*8 elems

  for (int kt = 0; kt < 1024; kt += 32) {
    __syncthreads();
    async16(A + (size_t)(m0 + srow) * 1024 + kt + scol, As + srow * 32 + scol);
    async16(A + (size_t)(m0 + 64 + srow) * 1024 + kt + scol, As + (64 + srow) * 32 + scol);
    async16(Bw + (size_t)(n0 + srow) * 1024 + kt + scol, Bs + srow * 32 + scol);
    async16(Bw + (size_t)(n0 + 64 + srow) * 1024 + kt + scol, Bs + (64 + srow) * 32 + scol);
    __syncthreads();
    bf16x8 af[4], bf[4];
#pragma unroll
    for (int i = 0; i < 4; ++i)
      af[i] = *(const bf16x8*)(As + (wm + i * 16 + l16) * 32 + quad * 8);
#pragma unroll
    for (int j = 0; j < 4; ++j)
      bf[j] = *(const bf16x8*)(Bs + (wn + j * 16 + l16) * 32 + quad * 8);
#pragma unroll
    for (int i = 0; i < 4; ++i)
#pragma unroll
      for (int j = 0; j < 4; ++j)
        acc[i][j] = __builtin_amdgcn_mfma_f32_16x16x32_bf16(af[i], bf[j], acc[i][j], 0, 0, 0);
  }
}

// QKV projection. kind=blockIdx.z: 0=Q (scaled by 1/8), 1=K, 2=V (transposed store).
__global__ __launch_bounds__(256) void qkv_gemm(
    const unsigned short* __restrict__ xb,
    const unsigned short* __restrict__ wqb, const unsigned short* __restrict__ wkb,
    const unsigned short* __restrict__ wvb,
    const float* __restrict__ bq, const float* __restrict__ bk, const float* __restrict__ bv,
    unsigned short* __restrict__ Q, unsigned short* __restrict__ Kd,
    unsigned short* __restrict__ Vt) {
  __shared__ unsigned short As[128 * 32], Bs[128 * 32];
  const int kind = blockIdx.z;
  const unsigned short* Bw = kind == 0 ? wqb : (kind == 1 ? wkb : wvb);
  const float* bias = kind == 0 ? bq : (kind == 1 ? bk : bv);
  const int m0 = blockIdx.y * 128, n0 = blockIdx.x * 128;
  f32x4 acc[4][4];
#pragma unroll
  for (int i = 0; i < 4; ++i)
#pragma unroll
    for (int j = 0; j < 4; ++j) { f32x4 z = {0.f, 0.f, 0.f, 0.f}; acc[i][j] = z; }
  gemm128_core(xb, Bw, m0, n0, acc, As, Bs);

  const int lane = threadIdx.x & 63, w = threadIdx.x >> 6;
  const int quad = lane >> 4, l16 = lane & 15;
  const int wm = (w >> 1) * 64, wn = (w & 1) * 64;
  const float scale = (kind == 0) ? 0.125f : 1.0f;
#pragma unroll
  for (int i = 0; i < 4; ++i) {
#pragma unroll
    for (int j = 0; j < 4; ++j) {
      const int col = n0 + wn + j * 16 + l16;         // channel e in [0,1024)
      const float bb = bias[col];
      const int h = col >> 6, d = col & 63;
#pragma unroll
      for (int r = 0; r < 4; ++r) {
        const int m = m0 + wm + i * 16 + quad * 4 + r; // token
        const int b = m >> 11, s = m & 2047;
        const int bh = b * 16 + h;
        const unsigned short val = f2bf((acc[i][j][r] + bb) * scale);
        if (kind == 0)      Q[((size_t)bh * SEQ + s) * 64 + d] = val;
        else if (kind == 1) Kd[((size_t)bh * SEQ + s) * 64 + d] = val;
        else                Vt[((size_t)bh * 64 + d) * SEQ + s] = val;
      }
    }
  }
}

// Flash attention + fused Gram-Schmidt exclusion.
// Q,K: [bh][s][64] bf16 (Q pre-scaled by 1/8); Vt: [bh][64][s] bf16.
// O out: [token][1024] bf16, token = b*SEQ+s, channel = h*64+d.
__global__ __launch_bounds__(256) void attn_kernel(
    const unsigned short* __restrict__ Q, const unsigned short* __restrict__ Kd,
    const unsigned short* __restrict__ Vt, unsigned short* __restrict__ O) {
  __shared__ unsigned short Qs[64 * 64], Ks[64 * 64], Vs[64 * 64], Ps[64 * 64];
  const int bh = blockIdx.y;
  const int q0 = blockIdx.x * 64;
  const int tid = threadIdx.x, lane = tid & 63, w = tid >> 6;
  const int quad = lane >> 4, l16 = lane & 15;
  const unsigned short* Qp = Q + (size_t)bh * SEQ * 64;
  const unsigned short* Kp = Kd + (size_t)bh * SEQ * 64;
  const unsigned short* Vp = Vt + (size_t)bh * 64 * SEQ;
  const int srow = tid >> 3, scol = (tid & 7) * 8;    // staging: flat = tid*8 elems

  async16(Qp + (size_t)(q0 + srow) * 64 + scol, Qs + srow * 64 + scol);
  async16(Qp + (size_t)(q0 + 32 + srow) * 64 + scol, Qs + (32 + srow) * 64 + scol);
  __syncthreads();
  bf16x8 aQ0 = *(const bf16x8*)(Qs + (w * 16 + l16) * 64 + quad * 8);
  bf16x8 aQ1 = *(const bf16x8*)(Qs + (w * 16 + l16) * 64 + 32 + quad * 8);

  f32x4 o_acc[4];
  float m_r[4], l_r[4];
#pragma unroll
  for (int n = 0; n < 4; ++n) { f32x4 z = {0.f, 0.f, 0.f, 0.f}; o_acc[n] = z; }
#pragma unroll
  for (int r = 0; r < 4; ++r) { m_r[r] = -1e30f; l_r[r] = 0.f; }

  for (int kt = 0; kt < SEQ; kt += 64) {
    __syncthreads();
    async16(Kp + (size_t)(kt + srow) * 64 + scol, Ks + srow * 64 + scol);
    async16(Kp + (size_t)(kt + 32 + srow) * 64 + scol, Ks + (32 + srow) * 64 + scol);
    async16(Vp + (size_t)srow * SEQ + kt + scol, Vs + srow * 64 + scol);
    async16(Vp + (size_t)(32 + srow) * SEQ + kt + scol, Vs + (32 + srow) * 64 + scol);
    __syncthreads();

    f32x4 st[4];
#pragma unroll
    for (int n = 0; n < 4; ++n) {
      f32x4 z = {0.f, 0.f, 0.f, 0.f};
      bf16x8 b0 = *(const bf16x8*)(Ks + (n * 16 + l16) * 64 + quad * 8);
      bf16x8 b1 = *(const bf16x8*)(Ks + (n * 16 + l16) * 64 + 32 + quad * 8);
      z = __builtin_amdgcn_mfma_f32_16x16x32_bf16(aQ0, b0, z, 0, 0, 0);
      z = __builtin_amdgcn_mfma_f32_16x16x32_bf16(aQ1, b1, z, 0, 0, 0);
      st[n] = z;
    }

    float alpha[4];
#pragma unroll
    for (int r = 0; r < 4; ++r) {
      float mx = fmaxf(fmaxf(st[0][r], st[1][r]), fmaxf(st[2][r], st[3][r]));
#pragma unroll
      for (int off = 1; off < 16; off <<= 1) mx = fmaxf(mx, __shfl_xor(mx, off, 64));
      const float mn = fmaxf(m_r[r], mx);
      alpha[r] = __expf(m_r[r] - mn);
      m_r[r] = mn;
      float rs = 0.f;
#pragma unroll
      for (int n = 0; n < 4; ++n) {
        const float p = __expf(st[n][r] - mn);
        st[n][r] = p;
        rs += p;
      }
#pragma unroll
      for (int off = 1; off < 16; off <<= 1) rs += __shfl_xor(rs, off, 64);
      l_r[r] = l_r[r] * alpha[r] + rs;
    }
#pragma unroll
    for (int n = 0; n < 4; ++n)
#pragma unroll
      for (int r = 0; r < 4; ++r) {
        Ps[(w * 16 + quad * 4 + r) * 64 + n * 16 + l16] = f2bf(st[n][r]);
        o_acc[n][r] *= alpha[r];
      }
    // wave reads only its own 16 rows of Ps -> no cross-wave barrier needed
    bf16x8 aP0 = *(const bf16x8*)(Ps + (w * 16 + l16) * 64 + quad * 8);
    bf16x8 aP1 = *(const bf16x8*)(Ps + (w * 16 + l16) * 64 + 32 + quad * 8);
#pragma unroll
    for (int n = 0; n < 4; ++n) {
      bf16x8 b0 = *(const bf16x8*)(Vs + (n * 16 + l16) * 64 + quad * 8);
      bf16x8 b1 = *(const bf16x8*)(Vs + (n * 16 + l16) * 64 + 32 + quad * 8);
      o_acc[n] = __builtin_amdgcn_mfma_f32_16x16x32_bf16(aP0, b0, o_acc[n], 0, 0, 0);
      o_acc[n] = __builtin_amdgcn_mfma_f32_16x16x32_bf16(aP1, b1, o_acc[n], 0, 0, 0);
    }
  }

  // epilogue: normalize, exclusion against diagonal v, write O[token][channel]
  const int b = bh >> 4, h = bh & 15;
  float ov[4] = {0.f, 0.f, 0.f, 0.f}, vv[4] = {0.f, 0.f, 0.f, 0.f};
  float vval[4][4];
#pragma unroll
  for (int n = 0; n < 4; ++n)
#pragma unroll
    for (int r = 0; r < 4; ++r) {
      const int s = q0 + w * 16 + quad * 4 + r;
      const int d = n * 16 + l16;
      const float vx = bf2f(Vp[(size_t)d * SEQ + s]);
      vval[n][r] = vx;
      const float o = o_acc[n][r] / l_r[r];
      o_acc[n][r] = o;
      ov[r] += o * vx;
      vv[r] += vx * vx;
    }
#pragma unroll
  for (int r = 0; r < 4; ++r) {
#pragma unroll
    for (int off = 1; off < 16; off <<= 1) {
      ov[r] += __shfl_xor(ov[r], off, 64);
      vv[r] += __shfl_xor(vv[r], off, 64);
    }
  }
#pragma unroll
  for (int n = 0; n < 4; ++n)
#pragma unroll
    for (int r = 0; r < 4; ++r) {
      const float align = ov[r] / (vv[r] + 1e-8f);
      const float o = o_acc[n][r] - align * vval[n][r];
      const int s = q0 + w * 16 + quad * 4 + r;
      const int token = b * SEQ + s;
      const int ch = h * 64 + n * 16 + l16;
      O[(size_t)token * DM + ch] = f2bf(o);
    }
}

// out = O @ Wo^T + bo, fp32 output
__global__ __launch_bounds__(256) void out_gemm(
    const unsigned short* __restrict__ Ob, const unsigned short* __restrict__ wob,
    const float* __restrict__ bo, float* __restrict__ out) {
  __shared__ unsigned short As[128 * 32], Bs[128 * 32];
  const int m0 = blockIdx.y * 128, n0 = blockIdx.x * 128;
  f32x4 acc[4][4];
#pragma unroll
  for (int i = 0; i < 4; ++i)
#pragma unroll
    for (int j = 0; j < 4; ++j) { f32x4 z = {0.f, 0.f, 0.f, 0.f}; acc[i][j] = z; }
  gemm128_core(Ob, wob, m0, n0, acc, As, Bs);

  const int lane = threadIdx.x & 63, w = threadIdx.x >> 6;
  const int quad = lane >> 4, l16 = lane & 15;
  const int wm = (w >> 1) * 64, wn = (w & 1) * 64;
#pragma unroll
  for (int i = 0; i < 4; ++i)
#pragma unroll
    for (int j = 0; j < 4; ++j) {
      const int col = n0 + wn + j * 16 + l16;
      const float bb = bo[col];
#pragma unroll
      for (int r = 0; r < 4; ++r) {
        const int m = m0 + wm + i * 16 + quad * 4 + r;
        out[(size_t)m * DM + col] = acc[i][j][r] + bb;
      }
    }
}

extern "C" void kernel_launch(void* const* d_in, const int* in_sizes, int n_in,
                              void* d_out, int out_size, void* d_ws, size_t ws_size,
                              hipStream_t stream) {
  const float* x  = (const float*)d_in[0];
  const float* wq = (const float*)d_in[1];
  const float* bq = (const float*)d_in[2];
  const float* wk = (const float*)d_in[3];
  const float* bk = (const float*)d_in[4];
  const float* wv = (const float*)d_in[5];
  const float* bv = (const float*)d_in[6];
  const float* wo = (const float*)d_in[7];
  const float* bo = (const float*)d_in[8];
  float* out = (float*)d_out;
  (void)in_sizes; (void)n_in; (void)out_size; (void)ws_size;

  unsigned short* ws  = (unsigned short*)d_ws;
  unsigned short* xb  = ws;                         // 4096*1024
  unsigned short* wqb = xb + (size_t)NTOK * DM;     // 1024*1024 each
  unsigned short* wkb = wqb + (size_t)DM * DM;
  unsigned short* wvb = wkb + (size_t)DM * DM;
  unsigned short* wob = wvb + (size_t)DM * DM;
  unsigned short* Qb  = wob + (size_t)DM * DM;      // [32][2048][64]
  unsigned short* Kb  = Qb + (size_t)NTOK * DM;
  unsigned short* Vtb = Kb + (size_t)NTOK * DM;     // [32][64][2048]
  unsigned short* Ob  = Vtb + (size_t)NTOK * DM;    // [4096][1024]

  cast_f32_bf16<<<4096, 256, 0, stream>>>(x, xb, NTOK * DM);
  cast_f32_bf16<<<1024, 256, 0, stream>>>(wq, wqb, DM * DM);
  cast_f32_bf16<<<1024, 256, 0, stream>>>(wk, wkb, DM * DM);
  cast_f32_bf16<<<1024, 256, 0, stream>>>(wv, wvb, DM * DM);
  cast_f32_bf16<<<1024, 256, 0, stream>>>(wo, wob, DM * DM);

  qkv_gemm<<<dim3(8, 32, 3), 256, 0, stream>>>(xb, wqb, wkb, wvb, bq, bk, bv, Qb, Kb, Vtb);
  attn_kernel<<<dim3(32, 32), 256, 0, stream>>>(Qb, Kb, Vtb, Ob);
  out_gemm<<<dim3(8, 32), 256, 0, stream>>>(Ob, wob, bo, out);
}

// Round 2
// 234.780 us; speedup vs baseline: 1.3060x; 1.3060x over previous
//
#include <hip/hip_runtime.h>
#include <stdint.h>

#define SEQ 2048
#define NTOK 4096          // B*S
#define DM 1024

typedef __bf16 bf16x8 __attribute__((ext_vector_type(8)));
typedef __bf16 bf16x4 __attribute__((ext_vector_type(4)));
typedef float f32x4 __attribute__((ext_vector_type(4)));

__device__ __forceinline__ unsigned short f2bf(float f) {
  union { float f; unsigned u; } v; v.f = f;
  return (unsigned short)((v.u + 0x7fffu + ((v.u >> 16) & 1u)) >> 16);
}
__device__ __forceinline__ float bf2f(unsigned short s) {
  union { unsigned u; float f; } v; v.u = ((unsigned)s) << 16; return v.f;
}

// async global->LDS, 16B per lane. LDS dest must be wave-uniform base + lane*16.
__device__ __forceinline__ void async16(const unsigned short* g, unsigned short* l) {
  __builtin_amdgcn_global_load_lds(
      (const __attribute__((address_space(1))) void*)g,
      (__attribute__((address_space(3))) void*)l, 16, 0, 0);
}

__global__ __launch_bounds__(256) void cast_f32_bf16(
    const float* __restrict__ src, unsigned short* __restrict__ dst, int n) {
  int i = (blockIdx.x * 256 + threadIdx.x) * 4;
  if (i + 3 < n) {
    float4 f = *(const float4*)(src + i);
    ushort4 o;
    o.x = f2bf(f.x); o.y = f2bf(f.y); o.z = f2bf(f.z); o.w = f2bf(f.w);
    *(ushort4*)(dst + i) = o;
  }
}

// ---- 128x128 GEMM core (m97 pattern): C[m,n] += sum_k A[m,k]*B[n,k] ----
__device__ __forceinline__ void gemm128_core(
    const unsigned short* __restrict__ A, const unsigned short* __restrict__ Bw,
    int m0, int n0, f32x4 acc[4][4], unsigned short* As, unsigned short* Bs) {
  const int tid = threadIdx.x;
  const int lane = tid & 63;
  const int w = tid >> 6;
  const int wm = (w >> 1) * 64, wn = (w & 1) * 64;
  const int quad = lane >> 4, l16 = lane & 15;
  const int srow = tid >> 2, scol = (tid & 3) * 8;

  for (int kt = 0; kt < 1024; kt += 32) {
    __syncthreads();
    async16(A + (size_t)(m0 + srow) * 1024 + kt + scol, As + srow * 32 + scol);
    async16(A + (size_t)(m0 + 64 + srow) * 1024 + kt + scol, As + (64 + srow) * 32 + scol);
    async16(Bw + (size_t)(n0 + srow) * 1024 + kt + scol, Bs + srow * 32 + scol);
    async16(Bw + (size_t)(n0 + 64 + srow) * 1024 + kt + scol, Bs + (64 + srow) * 32 + scol);
    __syncthreads();
    bf16x8 af[4], bf[4];
#pragma unroll
    for (int i = 0; i < 4; ++i)
      af[i] = *(const bf16x8*)(As + (wm + i * 16 + l16) * 32 + quad * 8);
#pragma unroll
    for (int j = 0; j < 4; ++j)
      bf[j] = *(const bf16x8*)(Bs + (wn + j * 16 + l16) * 32 + quad * 8);
#pragma unroll
    for (int i = 0; i < 4; ++i)
#pragma unroll
      for (int j = 0; j < 4; ++j)
        acc[i][j] = __builtin_amdgcn_mfma_f32_16x16x32_bf16(af[i], bf[j], acc[i][j], 0, 0, 0);
  }
}

// QKV projection. kind=blockIdx.z: 0=Q (scaled by 1/8), 1=K, 2=V (transposed store).
__global__ __launch_bounds__(256) void qkv_gemm(
    const unsigned short* __restrict__ xb,
    const unsigned short* __restrict__ wqb, const unsigned short* __restrict__ wkb,
    const unsigned short* __restrict__ wvb,
    const float* __restrict__ bq, const float* __restrict__ bk, const float* __restrict__ bv,
    unsigned short* __restrict__ Q, unsigned short* __restrict__ Kd,
    unsigned short* __restrict__ Vt) {
  __shared__ unsigned short As[128 * 32], Bs[128 * 32];
  const int kind = blockIdx.z;
  const unsigned short* Bw = kind == 0 ? wqb : (kind == 1 ? wkb : wvb);
  const float* bias = kind == 0 ? bq : (kind == 1 ? bk : bv);
  const int m0 = blockIdx.y * 128, n0 = blockIdx.x * 128;
  f32x4 acc[4][4];
#pragma unroll
  for (int i = 0; i < 4; ++i)
#pragma unroll
    for (int j = 0; j < 4; ++j) { f32x4 z = {0.f, 0.f, 0.f, 0.f}; acc[i][j] = z; }
  gemm128_core(xb, Bw, m0, n0, acc, As, Bs);

  const int lane = threadIdx.x & 63, w = threadIdx.x >> 6;
  const int quad = lane >> 4, l16 = lane & 15;
  const int wm = (w >> 1) * 64, wn = (w & 1) * 64;
  const float scale = (kind == 0) ? 0.125f : 1.0f;
#pragma unroll
  for (int i = 0; i < 4; ++i) {
#pragma unroll
    for (int j = 0; j < 4; ++j) {
      const int col = n0 + wn + j * 16 + l16;
      const float bb = bias[col];
      const int h = col >> 6, d = col & 63;
#pragma unroll
      for (int r = 0; r < 4; ++r) {
        const int m = m0 + wm + i * 16 + quad * 4 + r;
        const int b = m >> 11, s = m & 2047;
        const int bh = b * 16 + h;
        const unsigned short val = f2bf((acc[i][j][r] + bb) * scale);
        if (kind == 0)      Q[((size_t)bh * SEQ + s) * 64 + d] = val;
        else if (kind == 1) Kd[((size_t)bh * SEQ + s) * 64 + d] = val;
        else                Vt[((size_t)bh * 64 + d) * SEQ + s] = val;
      }
    }
  }
}

// Flash attention (S^T form) + fused Gram-Schmidt exclusion.
// Q,K: [bh][s][64] bf16 (Q pre-scaled by 1/8); Vt: [bh][64][s] bf16.
// LDS buffers are XOR-swizzled: 16B chunk c of row r stored at chunk c^(r&7).
// S^T = K*Q^T: C-frag gives lane (quad,l16): score[key=kt+kk*16+quad*4+r][q=l16].
// PV uses a permuted k-slot labeling so the B-operand (P) is the lane's own
// exp'd scores packed locally (no LDS round-trip); V's A-frag absorbs the
// permutation as two ds_read_b64 per tile.
__global__ __launch_bounds__(256) void attn_kernel(
    const unsigned short* __restrict__ Q, const unsigned short* __restrict__ Kd,
    const unsigned short* __restrict__ Vt, unsigned short* __restrict__ O) {
  __shared__ unsigned short Qs[64 * 64], Ks[64 * 64], Vs[64 * 64];
  const int bh = blockIdx.y;
  const int q0 = blockIdx.x * 64;
  const int tid = threadIdx.x, lane = tid & 63, w = tid >> 6;
  const int quad = lane >> 4, l16 = lane & 15;
  const unsigned short* Qp = Q + (size_t)bh * SEQ * 64;
  const unsigned short* Kp = Kd + (size_t)bh * SEQ * 64;
  const unsigned short* Vp = Vt + (size_t)bh * 64 * SEQ;
  const int srow = tid >> 3;                       // 0..31
  const int sc = ((tid & 7) ^ (srow & 7)) << 3;    // swizzled global elem offset

  // stage Q rows q0..q0+63 (swizzled)
  async16(Qp + (size_t)(q0 + srow) * 64 + sc, Qs + tid * 8);
  async16(Qp + (size_t)(q0 + 32 + srow) * 64 + sc, Qs + 2048 + tid * 8);
  __syncthreads();
  const int sel = l16 & 7;
  const int qrow = w * 16 + l16;
  bf16x8 bQ0 = *(const bf16x8*)(Qs + qrow * 64 + ((quad ^ sel) << 3));
  bf16x8 bQ1 = *(const bf16x8*)(Qs + qrow * 64 + (((4 + quad) ^ sel) << 3));

  f32x4 o_acc[4];
#pragma unroll
  for (int dt = 0; dt < 4; ++dt) { f32x4 z = {0.f, 0.f, 0.f, 0.f}; o_acc[dt] = z; }
  float m_r = -1e30f, l_r = 0.f;

  for (int kt = 0; kt < SEQ; kt += 64) {
    __syncthreads();
    async16(Kp + (size_t)(kt + srow) * 64 + sc, Ks + tid * 8);
    async16(Kp + (size_t)(kt + 32 + srow) * 64 + sc, Ks + 2048 + tid * 8);
    async16(Vp + (size_t)srow * SEQ + kt + sc, Vs + tid * 8);
    async16(Vp + (size_t)(32 + srow) * SEQ + kt + sc, Vs + 2048 + tid * 8);
    __syncthreads();

    // S^T: 4 key-tiles of 16, A=K rows, B=Q rows
    f32x4 st[4];
#pragma unroll
    for (int kk = 0; kk < 4; ++kk) {
      const int krow = kk * 16 + l16;
      bf16x8 a0 = *(const bf16x8*)(Ks + krow * 64 + ((quad ^ sel) << 3));
      bf16x8 a1 = *(const bf16x8*)(Ks + krow * 64 + (((4 + quad) ^ sel) << 3));
      f32x4 z = {0.f, 0.f, 0.f, 0.f};
      z = __builtin_amdgcn_mfma_f32_16x16x32_bf16(a0, bQ0, z, 0, 0, 0);
      z = __builtin_amdgcn_mfma_f32_16x16x32_bf16(a1, bQ1, z, 0, 0, 0);
      st[kk] = z;
    }

    // online softmax: one q per lane (q=l16), keys spread over quads+regs
    float mx = st[0][0];
#pragma unroll
    for (int kk = 0; kk < 4; ++kk)
#pragma unroll
      for (int r = 0; r < 4; ++r) mx = fmaxf(mx, st[kk][r]);
    mx = fmaxf(mx, __shfl_xor(mx, 16, 64));
    mx = fmaxf(mx, __shfl_xor(mx, 32, 64));
    const float mn = fmaxf(m_r, mx);
    const float alpha = __expf(m_r - mn);
    m_r = mn;
    float rs = 0.f;
#pragma unroll
    for (int kk = 0; kk < 4; ++kk)
#pragma unroll
      for (int r = 0; r < 4; ++r) {
        const float p = __expf(st[kk][r] - mn);
        st[kk][r] = p;
        rs += p;
      }
    rs += __shfl_xor(rs, 16, 64);
    rs += __shfl_xor(rs, 32, 64);
    l_r = l_r * alpha + rs;
#pragma unroll
    for (int dt = 0; dt < 4; ++dt) o_acc[dt] *= alpha;

    // pack P locally: B-frag slot (quad, j): j0-3 -> st[2G][j], j4-7 -> st[2G+1][j-4]
    bf16x8 bP[2];
#pragma unroll
    for (int G = 0; G < 2; ++G) {
      union { unsigned short u[8]; bf16x8 v; } pk;
#pragma unroll
      for (int r = 0; r < 4; ++r) {
        pk.u[r] = f2bf(st[2 * G][r]);
        pk.u[4 + r] = f2bf(st[2 * G + 1][r]);
      }
      bP[G] = pk.v;
    }

    // O^T += Vt * P : A slot (quad,j) must be V[key = 32G + (j>>2)*16 + quad*4 + (j&3)]
#pragma unroll
    for (int dt = 0; dt < 4; ++dt) {
      const int vrow = dt * 16 + l16;
      const unsigned short* vbase = Vs + vrow * 64;
      const int inner = (quad & 1) * 4;
#pragma unroll
      for (int G = 0; G < 2; ++G) {
        const int c0 = 4 * G + (quad >> 1);
        bf16x4 lo = *(const bf16x4*)(vbase + ((c0 ^ sel) << 3) + inner);
        bf16x4 hi = *(const bf16x4*)(vbase + (((c0 + 2) ^ sel) << 3) + inner);
        bf16x8 aV = __builtin_shufflevector(lo, hi, 0, 1, 2, 3, 4, 5, 6, 7);
        o_acc[dt] = __builtin_amdgcn_mfma_f32_16x16x32_bf16(aV, bP[G], o_acc[dt], 0, 0, 0);
      }
    }
  }

  // epilogue: lane holds O^T[d = dt*16+quad*4+r][q = l16] for q fixed
  const int b = bh >> 4, h = bh & 15;
  const int qg = q0 + w * 16 + l16;
  const float inv_l = 1.0f / l_r;
  float vval[4][4];
  float ov = 0.f, vv = 0.f;
#pragma unroll
  for (int dt = 0; dt < 4; ++dt)
#pragma unroll
    for (int r = 0; r < 4; ++r) {
      const int d = dt * 16 + quad * 4 + r;
      const float vx = bf2f(Vp[(size_t)d * SEQ + qg]);
      vval[dt][r] = vx;
      const float o = o_acc[dt][r] * inv_l;
      o_acc[dt][r] = o;
      ov += o * vx;
      vv += vx * vx;
    }
  ov += __shfl_xor(ov, 16, 64); ov += __shfl_xor(ov, 32, 64);
  vv += __shfl_xor(vv, 16, 64); vv += __shfl_xor(vv, 32, 64);
  const float align = ov / (vv + 1e-8f);
  const size_t base = (size_t)(b * SEQ + qg) * DM + h * 64;
#pragma unroll
  for (int dt = 0; dt < 4; ++dt) {
    ushort4 pk;
    pk.x = f2bf(o_acc[dt][0] - align * vval[dt][0]);
    pk.y = f2bf(o_acc[dt][1] - align * vval[dt][1]);
    pk.z = f2bf(o_acc[dt][2] - align * vval[dt][2]);
    pk.w = f2bf(o_acc[dt][3] - align * vval[dt][3]);
    *(ushort4*)(O + base + dt * 16 + quad * 4) = pk;
  }
}

// out = O @ Wo^T + bo, fp32 output
__global__ __launch_bounds__(256) void out_gemm(
    const unsigned short* __restrict__ Ob, const unsigned short* __restrict__ wob,
    const float* __restrict__ bo, float* __restrict__ out) {
  __shared__ unsigned short As[128 * 32], Bs[128 * 32];
  const int m0 = blockIdx.y * 128, n0 = blockIdx.x * 128;
  f32x4 acc[4][4];
#pragma unroll
  for (int i = 0; i < 4; ++i)
#pragma unroll
    for (int j = 0; j < 4; ++j) { f32x4 z = {0.f, 0.f, 0.f, 0.f}; acc[i][j] = z; }
  gemm128_core(Ob, wob, m0, n0, acc, As, Bs);

  const int lane = threadIdx.x & 63, w = threadIdx.x >> 6;
  const int quad = lane >> 4, l16 = lane & 15;
  const int wm = (w >> 1) * 64, wn = (w & 1) * 64;
#pragma unroll
  for (int i = 0; i < 4; ++i)
#pragma unroll
    for (int j = 0; j < 4; ++j) {
      const int col = n0 + wn + j * 16 + l16;
      const float bb = bo[col];
#pragma unroll
      for (int r = 0; r < 4; ++r) {
        const int m = m0 + wm + i * 16 + quad * 4 + r;
        out[(size_t)m * DM + col] = acc[i][j][r] + bb;
      }
    }
}

extern "C" void kernel_launch(void* const* d_in, const int* in_sizes, int n_in,
                              void* d_out, int out_size, void* d_ws, size_t ws_size,
                              hipStream_t stream) {
  const float* x  = (const float*)d_in[0];
  const float* wq = (const float*)d_in[1];
  const float* bq = (const float*)d_in[2];
  const float* wk = (const float*)d_in[3];
  const float* bk = (const float*)d_in[4];
  const float* wv = (const float*)d_in[5];
  const float* bv = (const float*)d_in[6];
  const float* wo = (const float*)d_in[7];
  const float* bo = (const float*)d_in[8];
  float* out = (float*)d_out;
  (void)in_sizes; (void)n_in; (void)out_size; (void)ws_size;

  unsigned short* ws  = (unsigned short*)d_ws;
  unsigned short* xb  = ws;                         // 4096*1024
  unsigned short* wqb = xb + (size_t)NTOK * DM;     // 1024*1024 each
  unsigned short* wkb = wqb + (size_t)DM * DM;
  unsigned short* wvb = wkb + (size_t)DM * DM;
  unsigned short* wob = wvb + (size_t)DM * DM;
  unsigned short* Qb  = wob + (size_t)DM * DM;      // [32][2048][64]
  unsigned short* Kb  = Qb + (size_t)NTOK * DM;
  unsigned short* Vtb = Kb + (size_t)NTOK * DM;     // [32][64][2048]
  unsigned short* Ob  = Vtb + (size_t)NTOK * DM;    // [4096][1024]

  cast_f32_bf16<<<4096, 256, 0, stream>>>(x, xb, NTOK * DM);
  cast_f32_bf16<<<1024, 256, 0, stream>>>(wq, wqb, DM * DM);
  cast_f32_bf16<<<1024, 256, 0, stream>>>(wk, wkb, DM * DM);
  cast_f32_bf16<<<1024, 256, 0, stream>>>(wv, wvb, DM * DM);
  cast_f32_bf16<<<1024, 256, 0, stream>>>(wo, wob, DM * DM);

  qkv_gemm<<<dim3(8, 32, 3), 256, 0, stream>>>(xb, wqb, wkb, wvb, bq, bk, bv, Qb, Kb, Vtb);
  attn_kernel<<<dim3(32, 32), 256, 0, stream>>>(Qb, Kb, Vtb, Ob);
  out_gemm<<<dim3(8, 32), 256, 0, stream>>>(Ob, wob, bo, out);
}

// Round 4
// 232.037 us; speedup vs baseline: 1.3215x; 1.0118x over previous
//
#include <hip/hip_runtime.h>
#include <stdint.h>

#define SEQ 2048
#define NTOK 4096          // B*S
#define DM 1024

typedef __bf16 bf16x8 __attribute__((ext_vector_type(8)));
typedef __bf16 bf16x4 __attribute__((ext_vector_type(4)));
typedef float f32x4 __attribute__((ext_vector_type(4)));

__device__ __forceinline__ unsigned short f2bf(float f) {
  union { float f; unsigned u; } v; v.f = f;
  return (unsigned short)((v.u + 0x7fffu + ((v.u >> 16) & 1u)) >> 16);
}
__device__ __forceinline__ float bf2f(unsigned short s) {
  union { unsigned u; float f; } v; v.u = ((unsigned)s) << 16; return v.f;
}
// pack two floats to packed bf16 (round-half-up) in ONE v_perm + 2 adds
__device__ __forceinline__ unsigned pkbf(float a, float b) {
  union { float f; unsigned u; } x, y; x.f = a; y.f = b;
  return __builtin_amdgcn_perm(y.u + 0x8000u, x.u + 0x8000u, 0x07060302u);
}

// async global->LDS, 16B per lane. LDS dest must be wave-uniform base + lane*16.
__device__ __forceinline__ void async16(const unsigned short* g, unsigned short* l) {
  __builtin_amdgcn_global_load_lds(
      (const __attribute__((address_space(1))) void*)g,
      (__attribute__((address_space(3))) void*)l, 16, 0, 0);
}

// one kernel casts x + all 4 weights (contiguous in ws)
__global__ __launch_bounds__(256) void cast_all(
    const float* __restrict__ x, const float* __restrict__ wq,
    const float* __restrict__ wk, const float* __restrict__ wv,
    const float* __restrict__ wo, unsigned short* __restrict__ dst) {
  size_t i = ((size_t)blockIdx.x * 256 + threadIdx.x) * 4;
  const float* src; size_t off;
  if (i < (size_t)NTOK * DM) { src = x; off = i; }
  else {
    size_t j = i - (size_t)NTOK * DM;
    int s = (int)(j >> 20);
    src = (s == 0) ? wq : (s == 1) ? wk : (s == 2) ? wv : wo;
    off = j & 1048575u;
  }
  float4 f = *(const float4*)(src + off);
  ushort4 o;
  o.x = f2bf(f.x); o.y = f2bf(f.y); o.z = f2bf(f.z); o.w = f2bf(f.w);
  *(ushort4*)(dst + i) = o;
}

// ---- 128x128 GEMM core (m97 pattern): C[m,n] += sum_k A[m,k]*B[n,k] ----
__device__ __forceinline__ void gemm128_core(
    const unsigned short* __restrict__ A, const unsigned short* __restrict__ Bw,
    int m0, int n0, f32x4 acc[4][4], unsigned short* As, unsigned short* Bs) {
  const int tid = threadIdx.x;
  const int lane = tid & 63;
  const int w = tid >> 6;
  const int wm = (w >> 1) * 64, wn = (w & 1) * 64;
  const int quad = lane >> 4, l16 = lane & 15;
  const int srow = tid >> 2, scol = (tid & 3) * 8;

  for (int kt = 0; kt < 1024; kt += 32) {
    __syncthreads();
    async16(A + (size_t)(m0 + srow) * 1024 + kt + scol, As + srow * 32 + scol);
    async16(A + (size_t)(m0 + 64 + srow) * 1024 + kt + scol, As + (64 + srow) * 32 + scol);
    async16(Bw + (size_t)(n0 + srow) * 1024 + kt + scol, Bs + srow * 32 + scol);
    async16(Bw + (size_t)(n0 + 64 + srow) * 1024 + kt + scol, Bs + (64 + srow) * 32 + scol);
    __syncthreads();
    bf16x8 af[4], bf[4];
#pragma unroll
    for (int i = 0; i < 4; ++i)
      af[i] = *(const bf16x8*)(As + (wm + i * 16 + l16) * 32 + quad * 8);
#pragma unroll
    for (int j = 0; j < 4; ++j)
      bf[j] = *(const bf16x8*)(Bs + (wn + j * 16 + l16) * 32 + quad * 8);
#pragma unroll
    for (int i = 0; i < 4; ++i)
#pragma unroll
      for (int j = 0; j < 4; ++j)
        acc[i][j] = __builtin_amdgcn_mfma_f32_16x16x32_bf16(af[i], bf[j], acc[i][j], 0, 0, 0);
  }
}

// QKV projection. kind 0=Q (scaled by log2e/8), 1=K, 2=V^T (A/B swapped so the
// [d][s]-layout store is coalesced like Q/K).
__global__ __launch_bounds__(256) void qkv_gemm(
    const unsigned short* __restrict__ xb,
    const unsigned short* __restrict__ wqb, const unsigned short* __restrict__ wkb,
    const unsigned short* __restrict__ wvb,
    const float* __restrict__ bq, const float* __restrict__ bk, const float* __restrict__ bv,
    unsigned short* __restrict__ Q, unsigned short* __restrict__ Kd,
    unsigned short* __restrict__ Vt) {
  __shared__ unsigned short As[128 * 32], Bs[128 * 32];
  const int kind = blockIdx.z;
  const unsigned short* A; const unsigned short* Bw;
  int m0, n0;
  if (kind == 2) { A = wvb; Bw = xb; m0 = blockIdx.x * 128; n0 = blockIdx.y * 128; }
  else { A = xb; Bw = (kind == 0) ? wqb : wkb; m0 = blockIdx.y * 128; n0 = blockIdx.x * 128; }
  f32x4 acc[4][4];
#pragma unroll
  for (int i = 0; i < 4; ++i)
#pragma unroll
    for (int j = 0; j < 4; ++j) { f32x4 z = {0.f, 0.f, 0.f, 0.f}; acc[i][j] = z; }
  gemm128_core(A, Bw, m0, n0, acc, As, Bs);

  const int lane = threadIdx.x & 63, w = threadIdx.x >> 6;
  const int quad = lane >> 4, l16 = lane & 15;
  const int wm = (w >> 1) * 64, wn = (w & 1) * 64;

  if (kind == 2) {
    // m = channel, n = token
#pragma unroll
    for (int i = 0; i < 4; ++i)
#pragma unroll
      for (int j = 0; j < 4; ++j) {
        const int n = n0 + wn + j * 16 + l16;
        const int tb = n >> 11, s = n & 2047;
#pragma unroll
        for (int r = 0; r < 4; ++r) {
          const int m = m0 + wm + i * 16 + quad * 4 + r;
          const int h = m >> 6, d = m & 63;
          Vt[((size_t)(tb * 16 + h) * 64 + d) * SEQ + s] = f2bf(acc[i][j][r] + bv[m]);
        }
      }
  } else {
    const float* bias = (kind == 0) ? bq : bk;
    const float scale = (kind == 0) ? 0.180336880f : 1.0f;  // log2(e)/8 for Q
#pragma unroll
    for (int i = 0; i < 4; ++i)
#pragma unroll
      for (int j = 0; j < 4; ++j) {
        const int col = n0 + wn + j * 16 + l16;
        const float bb = bias[col];
        const int h = col >> 6, d = col & 63;
#pragma unroll
        for (int r = 0; r < 4; ++r) {
          const int m = m0 + wm + i * 16 + quad * 4 + r;
          const int b = m >> 11, s = m & 2047;
          const int bh = b * 16 + h;
          const unsigned short val = f2bf((acc[i][j][r] + bb) * scale);
          if (kind == 0) Q[((size_t)bh * SEQ + s) * 64 + d] = val;
          else           Kd[((size_t)bh * SEQ + s) * 64 + d] = val;
        }
      }
  }
}

// Flash attention (S^T form, log2-domain softmax) + fused exclusion.
// q-tile 128/block: 4 waves x 32 q each (halves per-work LDS fragment reads).
// K/V double-buffered; 1 barrier per K-tile with prefetch hidden under compute.
// Softmax denominator via MFMA against a ones A-fragment (no add-chain/shuffle).
__global__ __launch_bounds__(256) void attn_kernel(
    const unsigned short* __restrict__ Q, const unsigned short* __restrict__ Kd,
    const unsigned short* __restrict__ Vt, unsigned short* __restrict__ O) {
  __shared__ unsigned short Qs[128 * 64];      // 16KB
  __shared__ unsigned short Ks[2][64 * 64];    // 16KB
  __shared__ unsigned short Vs[2][64 * 64];    // 16KB
  const int bh = blockIdx.y;
  const int q0 = blockIdx.x * 128;
  const int tid = threadIdx.x, lane = tid & 63, w = tid >> 6;
  const int quad = lane >> 4, l16 = lane & 15;
  const unsigned short* Qp = Q + (size_t)bh * SEQ * 64;
  const unsigned short* Kp = Kd + (size_t)bh * SEQ * 64;
  const unsigned short* Vp = Vt + (size_t)bh * 64 * SEQ;
  const int srow = tid >> 3;
  const int sc = ((tid & 7) ^ (srow & 7)) << 3;   // XOR-swizzled chunk

  // each 32-row group = 32*64 = 2048 elems (BUGFIX R3: was c*4096, OOB + gaps)
#pragma unroll
  for (int c = 0; c < 4; ++c)
    async16(Qp + (size_t)(q0 + c * 32 + srow) * 64 + sc, Qs + c * 2048 + tid * 8);
  async16(Kp + (size_t)srow * 64 + sc, Ks[0] + tid * 8);
  async16(Kp + (size_t)(32 + srow) * 64 + sc, Ks[0] + 2048 + tid * 8);
  async16(Vp + (size_t)srow * SEQ + sc, Vs[0] + tid * 8);
  async16(Vp + (size_t)(32 + srow) * SEQ + sc, Vs[0] + 2048 + tid * 8);
  __syncthreads();

  const int sel = l16 & 7;
  bf16x8 bQ[2][2];
#pragma unroll
  for (int qq = 0; qq < 2; ++qq) {
    const int qrow = w * 32 + qq * 16 + l16;
#pragma unroll
    for (int hh = 0; hh < 2; ++hh)
      bQ[qq][hh] = *(const bf16x8*)(Qs + qrow * 64 + (((hh * 4 + quad) ^ sel) << 3));
  }
  union { unsigned short u[8]; bf16x8 v; } one8;
#pragma unroll
  for (int t = 0; t < 8; ++t) one8.u[t] = 0x3F80;
  const bf16x8 aOnes = one8.v;

  f32x4 o_acc[2][4];
  f32x4 l_acc[2];
  float m_r[2];
#pragma unroll
  for (int qq = 0; qq < 2; ++qq) {
    f32x4 z = {0.f, 0.f, 0.f, 0.f};
    l_acc[qq] = z; m_r[qq] = -1e30f;
#pragma unroll
    for (int dt = 0; dt < 4; ++dt) o_acc[qq][dt] = z;
  }

  for (int it = 0; it < SEQ / 64; ++it) {
    const int cur = it & 1;
    if (it) __syncthreads();
    if (it + 1 < SEQ / 64) {
      const int kt = (it + 1) * 64, nb = (it + 1) & 1;
      async16(Kp + (size_t)(kt + srow) * 64 + sc, Ks[nb] + tid * 8);
      async16(Kp + (size_t)(kt + 32 + srow) * 64 + sc, Ks[nb] + 2048 + tid * 8);
      async16(Vp + (size_t)srow * SEQ + kt + sc, Vs[nb] + tid * 8);
      async16(Vp + (size_t)(32 + srow) * SEQ + kt + sc, Vs[nb] + 2048 + tid * 8);
    }

    // S^T: score[key = 16kk + quad*4 + r][q = w*32 + qq*16 + l16], log2-domain
    f32x4 st[2][4];
#pragma unroll
    for (int kk = 0; kk < 4; ++kk) {
      const int krow = kk * 16 + l16;
      bf16x8 a0 = *(const bf16x8*)(Ks[cur] + krow * 64 + ((quad ^ sel) << 3));
      bf16x8 a1 = *(const bf16x8*)(Ks[cur] + krow * 64 + (((4 + quad) ^ sel) << 3));
#pragma unroll
      for (int qq = 0; qq < 2; ++qq) {
        f32x4 z = {0.f, 0.f, 0.f, 0.f};
        z = __builtin_amdgcn_mfma_f32_16x16x32_bf16(a0, bQ[qq][0], z, 0, 0, 0);
        z = __builtin_amdgcn_mfma_f32_16x16x32_bf16(a1, bQ[qq][1], z, 0, 0, 0);
        st[qq][kk] = z;
      }
    }

    bf16x8 bP[2][2];
#pragma unroll
    for (int qq = 0; qq < 2; ++qq) {
      float mx = st[qq][0][0];
#pragma unroll
      for (int kk = 0; kk < 4; ++kk)
#pragma unroll
        for (int r = 0; r < 4; ++r) mx = fmaxf(mx, st[qq][kk][r]);
      mx = fmaxf(mx, __shfl_xor(mx, 16, 64));
      mx = fmaxf(mx, __shfl_xor(mx, 32, 64));
      const float mn = fmaxf(m_r[qq], mx);
      const float alpha = __builtin_amdgcn_exp2f(m_r[qq] - mn);
      m_r[qq] = mn;
#pragma unroll
      for (int kk = 0; kk < 4; ++kk)
#pragma unroll
        for (int r = 0; r < 4; ++r)
          st[qq][kk][r] = __builtin_amdgcn_exp2f(st[qq][kk][r] - mn);
#pragma unroll
      for (int G = 0; G < 2; ++G) {
        union { unsigned d[4]; bf16x8 v; } pk;
        pk.d[0] = pkbf(st[qq][2 * G][0], st[qq][2 * G][1]);
        pk.d[1] = pkbf(st[qq][2 * G][2], st[qq][2 * G][3]);
        pk.d[2] = pkbf(st[qq][2 * G + 1][0], st[qq][2 * G + 1][1]);
        pk.d[3] = pkbf(st[qq][2 * G + 1][2], st[qq][2 * G + 1][3]);
        bP[qq][G] = pk.v;
      }
      l_acc[qq][0] *= alpha;
#pragma unroll
      for (int dt = 0; dt < 4; ++dt) o_acc[qq][dt] *= alpha;
    }

    // denominator via ones-MFMA (C-layout row independent; element 0 is l)
#pragma unroll
    for (int qq = 0; qq < 2; ++qq)
#pragma unroll
      for (int G = 0; G < 2; ++G)
        l_acc[qq] = __builtin_amdgcn_mfma_f32_16x16x32_bf16(aOnes, bP[qq][G], l_acc[qq], 0, 0, 0);

    // O^T += Vt * P, permuted k-slot labeling; V frags shared across qq
#pragma unroll
    for (int dt = 0; dt < 4; ++dt) {
      const unsigned short* vbase = Vs[cur] + (dt * 16 + l16) * 64;
      const int inner = (quad & 1) * 4;
#pragma unroll
      for (int G = 0; G < 2; ++G) {
        const int c0 = 4 * G + (quad >> 1);
        bf16x4 lo = *(const bf16x4*)(vbase + ((c0 ^ sel) << 3) + inner);
        bf16x4 hi = *(const bf16x4*)(vbase + (((c0 + 2) ^ sel) << 3) + inner);
        bf16x8 aV = __builtin_shufflevector(lo, hi, 0, 1, 2, 3, 4, 5, 6, 7);
#pragma unroll
        for (int qq = 0; qq < 2; ++qq)
          o_acc[qq][dt] = __builtin_amdgcn_mfma_f32_16x16x32_bf16(aV, bP[qq][G], o_acc[qq][dt], 0, 0, 0);
      }
    }
  }

  // epilogue: normalize, exclusion vs diagonal v, write O[token][channel]
  const int b = bh >> 4, h = bh & 15;
#pragma unroll
  for (int qq = 0; qq < 2; ++qq) {
    const int qg = q0 + w * 32 + qq * 16 + l16;
    const float inv_l = 1.0f / l_acc[qq][0];
    float vval[4][4];
    float ov = 0.f, vv = 0.f;
#pragma unroll
    for (int dt = 0; dt < 4; ++dt)
#pragma unroll
      for (int r = 0; r < 4; ++r) {
        const int d = dt * 16 + quad * 4 + r;
        const float vx = bf2f(Vp[(size_t)d * SEQ + qg]);
        vval[dt][r] = vx;
        const float o = o_acc[qq][dt][r] * inv_l;
        o_acc[qq][dt][r] = o;
        ov += o * vx;
        vv += vx * vx;
      }
    ov += __shfl_xor(ov, 16, 64); ov += __shfl_xor(ov, 32, 64);
    vv += __shfl_xor(vv, 16, 64); vv += __shfl_xor(vv, 32, 64);
    const float align = ov / (vv + 1e-8f);
    const size_t base = (size_t)(b * SEQ + qg) * DM + h * 64;
#pragma unroll
    for (int dt = 0; dt < 4; ++dt) {
      ushort4 pk;
      pk.x = f2bf(o_acc[qq][dt][0] - align * vval[dt][0]);
      pk.y = f2bf(o_acc[qq][dt][1] - align * vval[dt][1]);
      pk.z = f2bf(o_acc[qq][dt][2] - align * vval[dt][2]);
      pk.w = f2bf(o_acc[qq][dt][3] - align * vval[dt][3]);
      *(ushort4*)(O + base + dt * 16 + quad * 4) = pk;
    }
  }
}

// out = O @ Wo^T + bo, fp32 output
__global__ __launch_bounds__(256) void out_gemm(
    const unsigned short* __restrict__ Ob, const unsigned short* __restrict__ wob,
    const float* __restrict__ bo, float* __restrict__ out) {
  __shared__ unsigned short As[128 * 32], Bs[128 * 32];
  const int m0 = blockIdx.y * 128, n0 = blockIdx.x * 128;
  f32x4 acc[4][4];
#pragma unroll
  for (int i = 0; i < 4; ++i)
#pragma unroll
    for (int j = 0; j < 4; ++j) { f32x4 z = {0.f, 0.f, 0.f, 0.f}; acc[i][j] = z; }
  gemm128_core(Ob, wob, m0, n0, acc, As, Bs);

  const int lane = threadIdx.x & 63, w = threadIdx.x >> 6;
  const int quad = lane >> 4, l16 = lane & 15;
  const int wm = (w >> 1) * 64, wn = (w & 1) * 64;
#pragma unroll
  for (int i = 0; i < 4; ++i)
#pragma unroll
    for (int j = 0; j < 4; ++j) {
      const int col = n0 + wn + j * 16 + l16;
      const float bb = bo[col];
#pragma unroll
      for (int r = 0; r < 4; ++r) {
        const int m = m0 + wm + i * 16 + quad * 4 + r;
        out[(size_t)m * DM + col] = acc[i][j][r] + bb;
      }
    }
}

extern "C" void kernel_launch(void* const* d_in, const int* in_sizes, int n_in,
                              void* d_out, int out_size, void* d_ws, size_t ws_size,
                              hipStream_t stream) {
  const float* x  = (const float*)d_in[0];
  const float* wq = (const float*)d_in[1];
  const float* bq = (const float*)d_in[2];
  const float* wk = (const float*)d_in[3];
  const float* bk = (const float*)d_in[4];
  const float* wv = (const float*)d_in[5];
  const float* bv = (const float*)d_in[6];
  const float* wo = (const float*)d_in[7];
  const float* bo = (const float*)d_in[8];
  float* out = (float*)d_out;
  (void)in_sizes; (void)n_in; (void)out_size; (void)ws_size;

  unsigned short* ws  = (unsigned short*)d_ws;
  unsigned short* xb  = ws;                         // 4096*1024
  unsigned short* wqb = xb + (size_t)NTOK * DM;     // 1024*1024 each (contiguous!)
  unsigned short* wkb = wqb + (size_t)DM * DM;
  unsigned short* wvb = wkb + (size_t)DM * DM;
  unsigned short* wob = wvb + (size_t)DM * DM;
  unsigned short* Qb  = wob + (size_t)DM * DM;      // [32][2048][64]
  unsigned short* Kb  = Qb + (size_t)NTOK * DM;
  unsigned short* Vtb = Kb + (size_t)NTOK * DM;     // [32][64][2048]
  unsigned short* Ob  = Vtb + (size_t)NTOK * DM;    // [4096][1024]

  cast_all<<<8192, 256, 0, stream>>>(x, wq, wk, wv, wo, ws);
  qkv_gemm<<<dim3(8, 32, 3), 256, 0, stream>>>(xb, wqb, wkb, wvb, bq, bk, bv, Qb, Kb, Vtb);
  attn_kernel<<<dim3(16, 32), 256, 0, stream>>>(Qb, Kb, Vtb, Ob);
  out_gemm<<<dim3(8, 32), 256, 0, stream>>>(Ob, wob, bo, out);
}

// Round 5
// 225.031 us; speedup vs baseline: 1.3626x; 1.0311x over previous
//
#include <hip/hip_runtime.h>
#include <stdint.h>

#define SEQ 2048
#define NTOK 4096          // B*S
#define DM 1024

typedef __bf16 bf16x8 __attribute__((ext_vector_type(8)));
typedef __bf16 bf16x4 __attribute__((ext_vector_type(4)));
typedef float f32x4 __attribute__((ext_vector_type(4)));

__device__ __forceinline__ unsigned short f2bf(float f) {
  union { float f; unsigned u; } v; v.f = f;
  return (unsigned short)((v.u + 0x7fffu + ((v.u >> 16) & 1u)) >> 16);
}
__device__ __forceinline__ float bf2f(unsigned short s) {
  union { unsigned u; float f; } v; v.u = ((unsigned)s) << 16; return v.f;
}
// pack two floats to packed bf16 (round-half-up) in ONE v_perm + 2 adds
__device__ __forceinline__ unsigned pkbf(float a, float b) {
  union { float f; unsigned u; } x, y; x.f = a; y.f = b;
  return __builtin_amdgcn_perm(y.u + 0x8000u, x.u + 0x8000u, 0x07060302u);
}

// async global->LDS, 16B per lane. LDS dest must be wave-uniform base + lane*16.
__device__ __forceinline__ void async16(const unsigned short* g, unsigned short* l) {
  __builtin_amdgcn_global_load_lds(
      (const __attribute__((address_space(1))) void*)g,
      (__attribute__((address_space(3))) void*)l, 16, 0, 0);
}

// one kernel casts x + all 4 weights (contiguous in ws)
__global__ __launch_bounds__(256) void cast_all(
    const float* __restrict__ x, const float* __restrict__ wq,
    const float* __restrict__ wk, const float* __restrict__ wv,
    const float* __restrict__ wo, unsigned short* __restrict__ dst) {
  size_t i = ((size_t)blockIdx.x * 256 + threadIdx.x) * 4;
  const float* src; size_t off;
  if (i < (size_t)NTOK * DM) { src = x; off = i; }
  else {
    size_t j = i - (size_t)NTOK * DM;
    int s = (int)(j >> 20);
    src = (s == 0) ? wq : (s == 1) ? wk : (s == 2) ? wv : wo;
    off = j & 1048575u;
  }
  float4 f = *(const float4*)(src + off);
  ushort4 o;
  o.x = f2bf(f.x); o.y = f2bf(f.y); o.z = f2bf(f.z); o.w = f2bf(f.w);
  *(ushort4*)(dst + i) = o;
}

// ---- 128x128 GEMM core (m97 pattern): C[m,n] += sum_k A[m,k]*B[n,k] ----
__device__ __forceinline__ void gemm128_core(
    const unsigned short* __restrict__ A, const unsigned short* __restrict__ Bw,
    int m0, int n0, f32x4 acc[4][4], unsigned short* As, unsigned short* Bs) {
  const int tid = threadIdx.x;
  const int lane = tid & 63;
  const int w = tid >> 6;
  const int wm = (w >> 1) * 64, wn = (w & 1) * 64;
  const int quad = lane >> 4, l16 = lane & 15;
  const int srow = tid >> 2, scol = (tid & 3) * 8;

  for (int kt = 0; kt < 1024; kt += 32) {
    __syncthreads();
    async16(A + (size_t)(m0 + srow) * 1024 + kt + scol, As + srow * 32 + scol);
    async16(A + (size_t)(m0 + 64 + srow) * 1024 + kt + scol, As + (64 + srow) * 32 + scol);
    async16(Bw + (size_t)(n0 + srow) * 1024 + kt + scol, Bs + srow * 32 + scol);
    async16(Bw + (size_t)(n0 + 64 + srow) * 1024 + kt + scol, Bs + (64 + srow) * 32 + scol);
    __syncthreads();
    bf16x8 af[4], bf[4];
#pragma unroll
    for (int i = 0; i < 4; ++i)
      af[i] = *(const bf16x8*)(As + (wm + i * 16 + l16) * 32 + quad * 8);
#pragma unroll
    for (int j = 0; j < 4; ++j)
      bf[j] = *(const bf16x8*)(Bs + (wn + j * 16 + l16) * 32 + quad * 8);
#pragma unroll
    for (int i = 0; i < 4; ++i)
#pragma unroll
      for (int j = 0; j < 4; ++j)
        acc[i][j] = __builtin_amdgcn_mfma_f32_16x16x32_bf16(af[i], bf[j], acc[i][j], 0, 0, 0);
  }
}

// QKV projection. kind 0=Q (scaled by log2e/8), 1=K, 2=V^T (A/B swapped so the
// [d][s]-layout store is coalesced like Q/K).
__global__ __launch_bounds__(256) void qkv_gemm(
    const unsigned short* __restrict__ xb,
    const unsigned short* __restrict__ wqb, const unsigned short* __restrict__ wkb,
    const unsigned short* __restrict__ wvb,
    const float* __restrict__ bq, const float* __restrict__ bk, const float* __restrict__ bv,
    unsigned short* __restrict__ Q, unsigned short* __restrict__ Kd,
    unsigned short* __restrict__ Vt) {
  __shared__ unsigned short As[128 * 32], Bs[128 * 32];
  const int kind = blockIdx.z;
  const unsigned short* A; const unsigned short* Bw;
  int m0, n0;
  if (kind == 2) { A = wvb; Bw = xb; m0 = blockIdx.x * 128; n0 = blockIdx.y * 128; }
  else { A = xb; Bw = (kind == 0) ? wqb : wkb; m0 = blockIdx.y * 128; n0 = blockIdx.x * 128; }
  f32x4 acc[4][4];
#pragma unroll
  for (int i = 0; i < 4; ++i)
#pragma unroll
    for (int j = 0; j < 4; ++j) { f32x4 z = {0.f, 0.f, 0.f, 0.f}; acc[i][j] = z; }
  gemm128_core(A, Bw, m0, n0, acc, As, Bs);

  const int lane = threadIdx.x & 63, w = threadIdx.x >> 6;
  const int quad = lane >> 4, l16 = lane & 15;
  const int wm = (w >> 1) * 64, wn = (w & 1) * 64;

  if (kind == 2) {
    // m = channel, n = token
#pragma unroll
    for (int i = 0; i < 4; ++i)
#pragma unroll
      for (int j = 0; j < 4; ++j) {
        const int n = n0 + wn + j * 16 + l16;
        const int tb = n >> 11, s = n & 2047;
#pragma unroll
        for (int r = 0; r < 4; ++r) {
          const int m = m0 + wm + i * 16 + quad * 4 + r;
          const int h = m >> 6, d = m & 63;
          Vt[((size_t)(tb * 16 + h) * 64 + d) * SEQ + s] = f2bf(acc[i][j][r] + bv[m]);
        }
      }
  } else {
    const float* bias = (kind == 0) ? bq : bk;
    const float scale = (kind == 0) ? 0.180336880f : 1.0f;  // log2(e)/8 for Q
#pragma unroll
    for (int i = 0; i < 4; ++i)
#pragma unroll
      for (int j = 0; j < 4; ++j) {
        const int col = n0 + wn + j * 16 + l16;
        const float bb = bias[col];
        const int h = col >> 6, d = col & 63;
#pragma unroll
        for (int r = 0; r < 4; ++r) {
          const int m = m0 + wm + i * 16 + quad * 4 + r;
          const int b = m >> 11, s = m & 2047;
          const int bh = b * 16 + h;
          const unsigned short val = f2bf((acc[i][j][r] + bb) * scale);
          if (kind == 0) Q[((size_t)bh * SEQ + s) * 64 + d] = val;
          else           Kd[((size_t)bh * SEQ + s) * 64 + d] = val;
        }
      }
  }
}

// Flash attention, split-K (2 key slices of 1024), S^T form, log2-domain.
// LDS = 4 x 8KB buffers only: K dbuf = KV[0/1], V dbuf = KV[2/3]. Q is staged
// into KV[1]+KV[3] (the buffers first overwritten by the it=0 prefetch),
// consumed into registers before the loop -> 32KB LDS, 4 blocks/CU, 16 waves/CU.
// Writes unnormalized partial O^T (fp32, [ksl][bh][d][q]) + m,l per q.
__global__ __launch_bounds__(256) void attn_kernel(
    const unsigned short* __restrict__ Q, const unsigned short* __restrict__ Kd,
    const unsigned short* __restrict__ Vt,
    float* __restrict__ Op, float* __restrict__ Mp, float* __restrict__ Lp) {
  __shared__ unsigned short KV[4][4096];   // 32KB total
  const int bh = blockIdx.y;
  const int q0 = blockIdx.x * 128;
  const int ksl = blockIdx.z;
  const int ks0 = ksl << 10;               // key slice base
  const int tid = threadIdx.x, lane = tid & 63, w = tid >> 6;
  const int quad = lane >> 4, l16 = lane & 15;
  const unsigned short* Qp = Q + (size_t)bh * SEQ * 64;
  const unsigned short* Kp = Kd + (size_t)bh * SEQ * 64;
  const unsigned short* Vp = Vt + (size_t)bh * 64 * SEQ;
  const int srow = tid >> 3;
  const int sc = ((tid & 7) ^ (srow & 7)) << 3;   // XOR-swizzled chunk

  // stage Q (rows q0..q0+127) into KV[1] (rows 0-63) and KV[3] (rows 64-127)
#pragma unroll
  for (int c = 0; c < 4; ++c)
    async16(Qp + (size_t)(q0 + c * 32 + srow) * 64 + sc,
            KV[(c < 2) ? 1 : 3] + (c & 1) * 2048 + tid * 8);
  async16(Kp + (size_t)(ks0 + srow) * 64 + sc, KV[0] + tid * 8);
  async16(Kp + (size_t)(ks0 + 32 + srow) * 64 + sc, KV[0] + 2048 + tid * 8);
  async16(Vp + (size_t)srow * SEQ + ks0 + sc, KV[2] + tid * 8);
  async16(Vp + (size_t)(32 + srow) * SEQ + ks0 + sc, KV[2] + 2048 + tid * 8);
  __syncthreads();

  const int sel = l16 & 7;
  const unsigned short* Qsrc = (w < 2) ? KV[1] : KV[3];
  bf16x8 bQ[2][2];
#pragma unroll
  for (int qq = 0; qq < 2; ++qq) {
    const int qrow = (w * 32 + qq * 16 + l16) & 63;
#pragma unroll
    for (int hh = 0; hh < 2; ++hh)
      bQ[qq][hh] = *(const bf16x8*)(Qsrc + qrow * 64 + (((hh * 4 + quad) ^ sel) << 3));
  }
  __syncthreads();   // all waves done reading Q before it=0 prefetch overwrites

  union { unsigned short u[8]; bf16x8 v; } one8;
#pragma unroll
  for (int t = 0; t < 8; ++t) one8.u[t] = 0x3F80;
  const bf16x8 aOnes = one8.v;

  f32x4 o_acc[2][4];
  f32x4 l_acc[2];
  float m_r[2];
#pragma unroll
  for (int qq = 0; qq < 2; ++qq) {
    f32x4 z = {0.f, 0.f, 0.f, 0.f};
    l_acc[qq] = z; m_r[qq] = -1e30f;
#pragma unroll
    for (int dt = 0; dt < 4; ++dt) o_acc[qq][dt] = z;
  }

  for (int it = 0; it < 16; ++it) {
    const int cur = it & 1;
    if (it) __syncthreads();
    if (it + 1 < 16) {
      const int kt = ks0 + (it + 1) * 64, nb = (it + 1) & 1;
      async16(Kp + (size_t)(kt + srow) * 64 + sc, KV[nb] + tid * 8);
      async16(Kp + (size_t)(kt + 32 + srow) * 64 + sc, KV[nb] + 2048 + tid * 8);
      async16(Vp + (size_t)srow * SEQ + kt + sc, KV[2 + nb] + tid * 8);
      async16(Vp + (size_t)(32 + srow) * SEQ + kt + sc, KV[2 + nb] + 2048 + tid * 8);
    }
    const unsigned short* Ks = KV[cur];
    const unsigned short* Vs = KV[2 + cur];

    // S^T: score[key = 16kk + quad*4 + r][q = w*32 + qq*16 + l16], log2-domain
    f32x4 st[2][4];
#pragma unroll
    for (int kk = 0; kk < 4; ++kk) {
      const int krow = kk * 16 + l16;
      bf16x8 a0 = *(const bf16x8*)(Ks + krow * 64 + ((quad ^ sel) << 3));
      bf16x8 a1 = *(const bf16x8*)(Ks + krow * 64 + (((4 + quad) ^ sel) << 3));
#pragma unroll
      for (int qq = 0; qq < 2; ++qq) {
        f32x4 z = {0.f, 0.f, 0.f, 0.f};
        z = __builtin_amdgcn_mfma_f32_16x16x32_bf16(a0, bQ[qq][0], z, 0, 0, 0);
        z = __builtin_amdgcn_mfma_f32_16x16x32_bf16(a1, bQ[qq][1], z, 0, 0, 0);
        st[qq][kk] = z;
      }
    }

    bf16x8 bP[2][2];
#pragma unroll
    for (int qq = 0; qq < 2; ++qq) {
      float mx = st[qq][0][0];
#pragma unroll
      for (int kk = 0; kk < 4; ++kk)
#pragma unroll
        for (int r = 0; r < 4; ++r) mx = fmaxf(mx, st[qq][kk][r]);
      mx = fmaxf(mx, __shfl_xor(mx, 16, 64));
      mx = fmaxf(mx, __shfl_xor(mx, 32, 64));
      const float mn = fmaxf(m_r[qq], mx);
      const float alpha = __builtin_amdgcn_exp2f(m_r[qq] - mn);
      m_r[qq] = mn;
#pragma unroll
      for (int kk = 0; kk < 4; ++kk)
#pragma unroll
        for (int r = 0; r < 4; ++r)
          st[qq][kk][r] = __builtin_amdgcn_exp2f(st[qq][kk][r] - mn);
#pragma unroll
      for (int G = 0; G < 2; ++G) {
        union { unsigned d[4]; bf16x8 v; } pk;
        pk.d[0] = pkbf(st[qq][2 * G][0], st[qq][2 * G][1]);
        pk.d[1] = pkbf(st[qq][2 * G][2], st[qq][2 * G][3]);
        pk.d[2] = pkbf(st[qq][2 * G + 1][0], st[qq][2 * G + 1][1]);
        pk.d[3] = pkbf(st[qq][2 * G + 1][2], st[qq][2 * G + 1][3]);
        bP[qq][G] = pk.v;
      }
      l_acc[qq][0] *= alpha;
#pragma unroll
      for (int dt = 0; dt < 4; ++dt) o_acc[qq][dt] *= alpha;
    }

    // denominator via ones-MFMA (all C rows identical = per-q sum)
#pragma unroll
    for (int qq = 0; qq < 2; ++qq)
#pragma unroll
      for (int G = 0; G < 2; ++G)
        l_acc[qq] = __builtin_amdgcn_mfma_f32_16x16x32_bf16(aOnes, bP[qq][G], l_acc[qq], 0, 0, 0);

    // O^T += Vt * P, permuted k-slot labeling; V frags shared across qq
#pragma unroll
    for (int dt = 0; dt < 4; ++dt) {
      const unsigned short* vbase = Vs + (dt * 16 + l16) * 64;
      const int inner = (quad & 1) * 4;
#pragma unroll
      for (int G = 0; G < 2; ++G) {
        const int c0 = 4 * G + (quad >> 1);
        bf16x4 lo = *(const bf16x4*)(vbase + ((c0 ^ sel) << 3) + inner);
        bf16x4 hi = *(const bf16x4*)(vbase + (((c0 + 2) ^ sel) << 3) + inner);
        bf16x8 aV = __builtin_shufflevector(lo, hi, 0, 1, 2, 3, 4, 5, 6, 7);
#pragma unroll
        for (int qq = 0; qq < 2; ++qq)
          o_acc[qq][dt] = __builtin_amdgcn_mfma_f32_16x16x32_bf16(aV, bP[qq][G], o_acc[qq][dt], 0, 0, 0);
      }
    }
  }

  // write partials: Op[ksl][bh][d][q] (fp32, unnormalized), Mp/Lp[ksl][bh][q]
  const size_t sb = (size_t)(ksl * 32 + bh);
#pragma unroll
  for (int qq = 0; qq < 2; ++qq) {
    const int qg = q0 + w * 32 + qq * 16 + l16;
#pragma unroll
    for (int dt = 0; dt < 4; ++dt)
#pragma unroll
      for (int r = 0; r < 4; ++r) {
        const int d = dt * 16 + quad * 4 + r;
        Op[(sb * 64 + d) * SEQ + qg] = o_acc[qq][dt][r];
      }
    if (quad == 0) {
      Mp[sb * SEQ + qg] = m_r[qq];
      Lp[sb * SEQ + qg] = l_acc[qq][0];
    }
  }
}

// combine 2 key-slice partials + Gram-Schmidt exclusion -> O bf16 [token][ch]
__global__ __launch_bounds__(128) void combine_kernel(
    const float* __restrict__ Op, const float* __restrict__ Mp,
    const float* __restrict__ Lp, const unsigned short* __restrict__ Vt,
    unsigned short* __restrict__ O) {
  const int bh = blockIdx.y;
  const int q = blockIdx.x * 128 + threadIdx.x;
  const size_t QC = (size_t)32 * SEQ;
  const size_t idx = (size_t)bh * SEQ + q;
  const float m1 = Mp[idx], m2 = Mp[QC + idx];
  const float l1 = Lp[idx], l2 = Lp[QC + idx];
  const float m = fmaxf(m1, m2);
  const float w1 = __builtin_amdgcn_exp2f(m1 - m);
  const float w2 = __builtin_amdgcn_exp2f(m2 - m);
  const float inv = 1.0f / (l1 * w1 + l2 * w2);
  const float* O1 = Op + (size_t)bh * 64 * SEQ + q;
  const float* O2 = O1 + QC * 64;
  const unsigned short* Vp = Vt + (size_t)bh * 64 * SEQ + q;
  float o64[64];
  float ov = 0.f, vv = 0.f;
#pragma unroll
  for (int d = 0; d < 64; ++d) {
    const float o = (O1[(size_t)d * SEQ] * w1 + O2[(size_t)d * SEQ] * w2) * inv;
    const float v = bf2f(Vp[(size_t)d * SEQ]);
    o64[d] = o; ov += o * v; vv += v * v;
  }
  const float align = ov / (vv + 1e-8f);
  const int b = bh >> 4, h = bh & 15;
  unsigned short* dst = O + (size_t)(b * SEQ + q) * DM + h * 64;
#pragma unroll
  for (int d = 0; d < 64; d += 2) {
    const float a0 = o64[d]     - align * bf2f(Vp[(size_t)d * SEQ]);
    const float a1 = o64[d + 1] - align * bf2f(Vp[(size_t)(d + 1) * SEQ]);
    *(unsigned*)(dst + d) = pkbf(a0, a1);
  }
}

// out = O @ Wo^T + bo, fp32 output. 64x128 tiles -> 512 blocks = 2/CU.
__global__ __launch_bounds__(256) void out_gemm(
    const unsigned short* __restrict__ Ob, const unsigned short* __restrict__ wob,
    const float* __restrict__ bo, float* __restrict__ out) {
  __shared__ unsigned short As[64 * 32], Bs[128 * 32];
  const int m0 = blockIdx.y * 64, n0 = blockIdx.x * 128;
  const int tid = threadIdx.x, lane = tid & 63, w = tid >> 6;
  const int wm = (w >> 1) * 32, wn = (w & 1) * 64;
  const int quad = lane >> 4, l16 = lane & 15;
  const int srow = tid >> 2, scol = (tid & 3) * 8;
  f32x4 acc[2][4];
#pragma unroll
  for (int i = 0; i < 2; ++i)
#pragma unroll
    for (int j = 0; j < 4; ++j) { f32x4 z = {0.f, 0.f, 0.f, 0.f}; acc[i][j] = z; }

  for (int kt = 0; kt < 1024; kt += 32) {
    __syncthreads();
    async16(Ob + (size_t)(m0 + srow) * 1024 + kt + scol, As + srow * 32 + scol);
    async16(wob + (size_t)(n0 + srow) * 1024 + kt + scol, Bs + srow * 32 + scol);
    async16(wob + (size_t)(n0 + 64 + srow) * 1024 + kt + scol, Bs + (64 + srow) * 32 + scol);
    __syncthreads();
    bf16x8 af[2], bf[4];
#pragma unroll
    for (int i = 0; i < 2; ++i)
      af[i] = *(const bf16x8*)(As + (wm + i * 16 + l16) * 32 + quad * 8);
#pragma unroll
    for (int j = 0; j < 4; ++j)
      bf[j] = *(const bf16x8*)(Bs + (wn + j * 16 + l16) * 32 + quad * 8);
#pragma unroll
    for (int i = 0; i < 2; ++i)
#pragma unroll
      for (int j = 0; j < 4; ++j)
        acc[i][j] = __builtin_amdgcn_mfma_f32_16x16x32_bf16(af[i], bf[j], acc[i][j], 0, 0, 0);
  }

#pragma unroll
  for (int i = 0; i < 2; ++i)
#pragma unroll
    for (int j = 0; j < 4; ++j) {
      const int col = n0 + wn + j * 16 + l16;
      const float bb = bo[col];
#pragma unroll
      for (int r = 0; r < 4; ++r) {
        const int m = m0 + wm + i * 16 + quad * 4 + r;
        out[(size_t)m * DM + col] = acc[i][j][r] + bb;
      }
    }
}

extern "C" void kernel_launch(void* const* d_in, const int* in_sizes, int n_in,
                              void* d_out, int out_size, void* d_ws, size_t ws_size,
                              hipStream_t stream) {
  const float* x  = (const float*)d_in[0];
  const float* wq = (const float*)d_in[1];
  const float* bq = (const float*)d_in[2];
  const float* wk = (const float*)d_in[3];
  const float* bk = (const float*)d_in[4];
  const float* wv = (const float*)d_in[5];
  const float* bv = (const float*)d_in[6];
  const float* wo = (const float*)d_in[7];
  const float* bo = (const float*)d_in[8];
  float* out = (float*)d_out;
  (void)in_sizes; (void)n_in; (void)out_size; (void)ws_size;

  unsigned short* ws  = (unsigned short*)d_ws;
  unsigned short* xb  = ws;                         // 4096*1024
  unsigned short* wqb = xb + (size_t)NTOK * DM;     // 1024*1024 each (contiguous!)
  unsigned short* wkb = wqb + (size_t)DM * DM;
  unsigned short* wvb = wkb + (size_t)DM * DM;
  unsigned short* wob = wvb + (size_t)DM * DM;
  unsigned short* Qb  = wob + (size_t)DM * DM;      // [32][2048][64]
  unsigned short* Kb  = Qb + (size_t)NTOK * DM;
  unsigned short* Vtb = Kb + (size_t)NTOK * DM;     // [32][64][2048]
  unsigned short* Ob  = Vtb + (size_t)NTOK * DM;    // [4096][1024]
  float* Opw = (float*)(Ob + (size_t)NTOK * DM);    // [2][32][64][2048] fp32
  float* Mpw = Opw + (size_t)2 * 32 * 64 * SEQ;     // [2][32][2048]
  float* Lpw = Mpw + (size_t)2 * 32 * SEQ;

  cast_all<<<8192, 256, 0, stream>>>(x, wq, wk, wv, wo, ws);
  qkv_gemm<<<dim3(8, 32, 3), 256, 0, stream>>>(xb, wqb, wkb, wvb, bq, bk, bv, Qb, Kb, Vtb);
  attn_kernel<<<dim3(16, 32, 2), 256, 0, stream>>>(Qb, Kb, Vtb, Opw, Mpw, Lpw);
  combine_kernel<<<dim3(16, 32), 128, 0, stream>>>(Opw, Mpw, Lpw, Vtb, Ob);
  out_gemm<<<dim3(8, 64), 256, 0, stream>>>(Ob, wob, bo, out);
}